// Round 4
// baseline (68.060 us; speedup 1.0000x reference)
//
#include <hip/hip_runtime.h>
#include <hip/hip_fp16.h>

#define D 128

typedef __attribute__((ext_vector_type(8))) _Float16 f16x8;
typedef __attribute__((ext_vector_type(4))) _Float16 f16x4;
typedef __attribute__((ext_vector_type(2))) _Float16 f16x2;
typedef __attribute__((ext_vector_type(4))) float    f32x4;

union F16x8U { _Float16 h[8]; f16x8 v; };

// ---------------------------------------------------------------------------
// Kernel 0: metric -> fragment-ordered fp16 hi/lo B-fragments.
// Chunk q = (kk*8+cf)*64+lane holds B[k0+j][col], col=cf*16+(lane&15),
// k0=kk*32+(lane>>4)*8  == exactly the 16x16x32 MFMA B-operand layout.
// Two-level fp16 split: M = Mh + Ml with |residual| ~ 2^-22 |M|.
// ---------------------------------------------------------------------------
__global__ __launch_bounds__(256) void convert_M16(
    const float* __restrict__ M,
    _Float16* __restrict__ mh, _Float16* __restrict__ ml)
{
    const int q    = blockIdx.x * 256 + threadIdx.x;  // [0, 2048)
    const int kk   = q >> 9;
    const int cf   = (q >> 6) & 7;
    const int lane = q & 63;
    const int col  = cf * 16 + (lane & 15);
    const int k0   = kk * 32 + (lane >> 4) * 8;

    F16x8U h, l;
    #pragma unroll
    for (int j = 0; j < 8; ++j) {
        float f = M[(k0 + j) * D + col];
        _Float16 hh = (_Float16)f;
        h.h[j] = hh;
        l.h[j] = (_Float16)(f - (float)hh);
    }
    *(f16x8*)(mh + q * 8) = h.v;
    *(f16x8*)(ml + q * 8) = l.v;
}

// ---------------------------------------------------------------------------
// Shared column permutation (gather dot is order-invariant):
// within each 32-col group g: pos(c) = (c&15)*2 + ((c>>4)&1).
// E-epilogue: thread's (cfl=0,1) pair -> adjacent fp16 -> dense 4B stores.
// N-convert: cols (g*32+4v+t, g*32+16+4v+t) interleave -> dense 16B stores.
// ---------------------------------------------------------------------------
#define NE 3125   // E blocks: 32 rows each (100000 = 3125*32 exact)

__global__ __launch_bounds__(256) void fused_prep2(
    const float* __restrict__ E, const float* __restrict__ N,
    const _Float16* __restrict__ mh, const _Float16* __restrict__ ml,
    _Float16* __restrict__ Ep, _Float16* __restrict__ Np)
{
    const int tid = threadIdx.x;

    if ((int)blockIdx.x >= NE) {
        // ---- N-convert: 32 rows/block, 2 rows/thread, fully coalesced ----
        const int nb = blockIdx.x - NE;
        const int g  = (tid >> 2) & 3;   // 32-col group
        const int v  = tid & 3;          // 4-col sub-chunk
        #pragma unroll
        for (int rr = 0; rr < 2; ++rr) {
            const int row = nb * 32 + (tid >> 4) * 2 + rr;
            const float* base = N + (size_t)row * D + g * 32 + v * 4;
            const f32x4 a = *(const f32x4*)base;        // cols +0..3
            const f32x4 b = *(const f32x4*)(base + 16); // cols +16..19
            F16x8U o;
            o.h[0] = (_Float16)a.x; o.h[1] = (_Float16)b.x;
            o.h[2] = (_Float16)a.y; o.h[3] = (_Float16)b.y;
            o.h[4] = (_Float16)a.z; o.h[5] = (_Float16)b.z;
            o.h[6] = (_Float16)a.w; o.h[7] = (_Float16)b.w;
            *(f16x8*)(Np + (size_t)row * D + g * 32 + v * 8) = o.v;
        }
        return;
    }

    // ---- E-path: 32 rows x 128 cols per block; wave wid owns 32 cols ----
    const int lane = tid & 63;
    const int wid  = tid >> 6;        // 0..3 -> cols wid*32..+31
    const int lrow = lane & 15;
    const int lk   = lane >> 4;       // 0..3
    const int rb   = blockIdx.x * 32;

    // B fragments: loaded ONCE, held in registers for the whole K-loop.
    // cf_global = wid*2 + cfl; 16 frags = 64 VGPR.
    f16x8 bh[4][2], bl[4][2];
    #pragma unroll
    for (int kk = 0; kk < 4; ++kk)
        #pragma unroll
        for (int cfl = 0; cfl < 2; ++cfl) {
            const int off = ((kk * 8 + wid * 2 + cfl) * 64 + lane) * 8;
            bh[kk][cfl] = *(const f16x8*)(mh + off);
            bl[kk][cfl] = *(const f16x8*)(ml + off);
        }

    f32x4 acc[2][2];
    #pragma unroll
    for (int rf = 0; rf < 2; ++rf)
        #pragma unroll
        for (int cfl = 0; cfl < 2; ++cfl)
            acc[rf][cfl] = (f32x4){0.f, 0.f, 0.f, 0.f};

    #pragma unroll
    for (int kk = 0; kk < 4; ++kk) {
        // A fragment: row = rb + rf*16 + lrow, k = kk*32 + lk*8 + j
        F16x8U a16[2];
        #pragma unroll
        for (int rf = 0; rf < 2; ++rf) {
            const int row = rb + rf * 16 + lrow;
            const f32x4* p = (const f32x4*)(E + (size_t)row * D + kk * 32 + lk * 8);
            const f32x4 x = p[0], y = p[1];
            a16[rf].h[0] = (_Float16)x.x; a16[rf].h[1] = (_Float16)x.y;
            a16[rf].h[2] = (_Float16)x.z; a16[rf].h[3] = (_Float16)x.w;
            a16[rf].h[4] = (_Float16)y.x; a16[rf].h[5] = (_Float16)y.y;
            a16[rf].h[6] = (_Float16)y.z; a16[rf].h[7] = (_Float16)y.w;
        }
        // Two-term split accumulate: A16@Mh + A16@Ml
        #pragma unroll
        for (int rf = 0; rf < 2; ++rf)
            #pragma unroll
            for (int cfl = 0; cfl < 2; ++cfl) {
                acc[rf][cfl] = __builtin_amdgcn_mfma_f32_16x16x32_f16(
                    a16[rf].v, bh[kk][cfl], acc[rf][cfl], 0, 0, 0);
                acc[rf][cfl] = __builtin_amdgcn_mfma_f32_16x16x32_f16(
                    a16[rf].v, bl[kk][cfl], acc[rf][cfl], 0, 0, 0);
            }
    }

    // Epilogue: C/D layout col=lane&15, row=(lane>>4)*4+i (m89-verified).
    // Store pos = wid*32 + lrow*2 + cfl -> 4B per thread, 64B dense per
    // 16-lane group.
    #pragma unroll
    for (int rf = 0; rf < 2; ++rf)
        #pragma unroll
        for (int i = 0; i < 4; ++i) {
            const int row = rb + rf * 16 + lk * 4 + i;
            f16x2 o;
            o[0] = (_Float16)acc[rf][0][i];
            o[1] = (_Float16)acc[rf][1][i];
            *(f16x2*)(Ep + (size_t)row * D + wid * 32 + lrow * 2) = o;
        }
}

// ---------------------------------------------------------------------------
// Kernel 2: out[b] = sigmoid(2 * dot16(Ep[xs[b]], Np[ys[b]]) - 1).
// 16 lanes per output, 2 outputs per lane-group, fp32 accumulate.
// ---------------------------------------------------------------------------
__global__ __launch_bounds__(256) void gather_dot16(
    const int* __restrict__ xs, const int* __restrict__ ys,
    const _Float16* __restrict__ Ep, const _Float16* __restrict__ Np,
    float* __restrict__ out)
{
    const int tid = threadIdx.x;
    const int o0  = blockIdx.x * 32 + (tid >> 4) * 2;
    const int l   = tid & 15;

    const int x0 = xs[o0], x1 = xs[o0 + 1];
    const int y0 = ys[o0], y1 = ys[o0 + 1];

    const f16x8 a0 = *(const f16x8*)(Ep + (size_t)x0 * D + l * 8);
    const f16x8 b0 = *(const f16x8*)(Np + (size_t)y0 * D + l * 8);
    const f16x8 a1 = *(const f16x8*)(Ep + (size_t)x1 * D + l * 8);
    const f16x8 b1 = *(const f16x8*)(Np + (size_t)y1 * D + l * 8);

    float r0 = 0.f, r1 = 0.f;
    #pragma unroll
    for (int j = 0; j < 8; ++j) {
        r0 += (float)a0[j] * (float)b0[j];
        r1 += (float)a1[j] * (float)b1[j];
    }

    r0 += __shfl_xor(r0, 1); r1 += __shfl_xor(r1, 1);
    r0 += __shfl_xor(r0, 2); r1 += __shfl_xor(r1, 2);
    r0 += __shfl_xor(r0, 4); r1 += __shfl_xor(r1, 4);
    r0 += __shfl_xor(r0, 8); r1 += __shfl_xor(r1, 8);

    if (l == 0) {
        float2 v;
        v.x = 1.0f / (1.0f + __expf(1.0f - 2.0f * r0));
        v.y = 1.0f / (1.0f + __expf(1.0f - 2.0f * r1));
        *(float2*)(out + o0) = v;
    }
}

extern "C" void kernel_launch(void* const* d_in, const int* in_sizes, int n_in,
                              void* d_out, int out_size, void* d_ws, size_t ws_size,
                              hipStream_t stream) {
    const int*   xs     = (const int*)d_in[0];
    const int*   ys     = (const int*)d_in[1];
    const float* metric = (const float*)d_in[2];
    const float* EMBEDM = (const float*)d_in[3];
    const float* NEGEM  = (const float*)d_in[4];
    float*       out    = (float*)d_out;

    const int B = in_sizes[0];  // 262144

    // d_ws layout (256 MiB): Ep16 25.6MB @0, Np16 25.6MB @32MB,
    // M-frag fp16 hi/lo 32KB each @64MB.
    char* ws = (char*)d_ws;
    _Float16* Ep = (_Float16*)ws;
    _Float16* Np = (_Float16*)(ws + (32u << 20));
    _Float16* mh = (_Float16*)(ws + (64u << 20));
    _Float16* ml = (_Float16*)(ws + (64u << 20) + (64u << 10));

    convert_M16<<<8, 256, 0, stream>>>(metric, mh, ml);

    fused_prep2<<<NE + NE, 256, 0, stream>>>(EMBEDM, NEGEM, mh, ml, Ep, Np);

    gather_dot16<<<B / 32, 256, 0, stream>>>(xs, ys, Ep, Np, out);
}

// Round 6
// 60.421 us; speedup vs baseline: 1.1264x; 1.1264x over previous
//
#include <hip/hip_runtime.h>
#include <hip/hip_fp16.h>

#define D      128
#define NROWS  100000
#define RB     128                      // rows per E-block
#define NE     ((NROWS + RB - 1) / RB)  // 782
#define NN     (NROWS / 16)             // 6250

typedef __attribute__((ext_vector_type(8))) _Float16 f16x8;
typedef __attribute__((ext_vector_type(4))) float    f32x4;

union F16x8U { _Float16 h[8]; f16x8 v; };
union F32x4U { float f[4]; f32x4 v; };

typedef __attribute__((address_space(1))) const void gvoid;
typedef __attribute__((address_space(3))) void       lvoid;

// ---------------------------------------------------------------------------
// Kernel 0: metric -> fragment-ordered fp16 hi/lo B-fragments.
// Chunk q = (kk*8+cf)*64+lane holds B[k0+j][col], col=cf*16+(lane&15),
// k0=kk*32+(lane>>4)*8  == the 16x16x32 MFMA B-operand layout.
// fp16 two-term split: M = Mh + Ml, |residual| ~ 2^-22 |M|.
// ---------------------------------------------------------------------------
__global__ __launch_bounds__(256) void convert_M16(
    const float* __restrict__ M,
    _Float16* __restrict__ mh, _Float16* __restrict__ ml)
{
    const int q    = blockIdx.x * 256 + threadIdx.x;  // [0, 2048)
    const int kk   = q >> 9;
    const int cf   = (q >> 6) & 7;
    const int lane = q & 63;
    const int col  = cf * 16 + (lane & 15);
    const int k0   = kk * 32 + (lane >> 4) * 8;

    F16x8U h, l;
    #pragma unroll
    for (int j = 0; j < 8; ++j) {
        float f = M[(k0 + j) * D + col];
        _Float16 hh = (_Float16)f;
        h.h[j] = hh;
        l.h[j] = (_Float16)(f - (float)hh);
    }
    *(f16x8*)(mh + q * 8) = h.v;
    *(f16x8*)(ml + q * 8) = l.v;
}

// ---------------------------------------------------------------------------
// Kernel 1: N -> fp16 in pi order, pi(c) = (c&15)*8 + (c>>4).
// LDS-free (full occupancy). 16 rows/block; thread (row, l16) reads 8 dwords
// at stride 64B (cols l16+16k, coalesced across the 16 lanes) -> one 16B store.
// ---------------------------------------------------------------------------
__global__ __launch_bounds__(256) void conv_N(
    const float* __restrict__ N, _Float16* __restrict__ Np)
{
    const int l16 = threadIdx.x & 15;
    const int row = blockIdx.x * 16 + (threadIdx.x >> 4);   // exact: NN*16 = NROWS
    const float* src = N + (size_t)row * D + l16;
    F16x8U o;
    #pragma unroll
    for (int k = 0; k < 8; ++k) o.h[k] = (_Float16)src[16 * k];
    *(f16x8*)(Np + (size_t)row * D + l16 * 8) = o.v;
}

// ---------------------------------------------------------------------------
// Kernel 2: E' = E @ M (two-term fp16 MFMA), output fp16 in pi order.
// 128 rows x 128 cols per block, 4 waves; wave w owns rows [w*32, w*32+32).
// Stage via global_load_lds (async, no VGPR round-trip), then the PROVEN m97
// drain: s_waitcnt vmcnt(0) + __syncthreads() (R5's per-wave-drain-no-barrier
// variant raced under graph replay). LDS XOR-swizzle (16B slot u = t^(r&15))
// applied via pre-swizzled GLOBAL source (m173) so ds_read_b128 is
// conflict-free; B fragments double-buffered in VGPRs.
// ---------------------------------------------------------------------------
__global__ __launch_bounds__(256, 2) void gemm_E(
    const float* __restrict__ E,
    const _Float16* __restrict__ mh, const _Float16* __restrict__ ml,
    _Float16* __restrict__ Ep)
{
    __shared__ float lds[RB * D];   // 64 KB

    const int tid  = threadIdx.x;
    const int lane = tid & 63;
    const int w    = tid >> 6;
    const int rb   = (int)blockIdx.x * RB;
    const int lrow = lane & 15;
    const int lk   = lane >> 4;

    // Stage: 16B-slot S = w*1024 + i*64 + lane; r = S>>5; t = S&31;
    // global slot u = t ^ (r&15); LDS dest linear (wave-uniform base+lane*16).
    #pragma unroll
    for (int i = 0; i < 16; ++i) {
        const int S  = w * 1024 + i * 64 + lane;
        const int r  = S >> 5;
        const int u  = (S & 31) ^ (r & 15);
        const int gr = min(rb + r, NROWS - 1);          // tail clamp
        const float* src = E + (size_t)gr * D + u * 4;
        __builtin_amdgcn_global_load_lds(
            (gvoid*)src, (lvoid*)&lds[(w * 1024 + i * 64) * 4], 16, 0, 0);
    }

    // B fragments for kk=0 (L2-hot), issued before the drain.
    f16x8 bh[2][8], bl[2][8];
    #pragma unroll
    for (int cf = 0; cf < 8; ++cf) {
        const int off = (cf * 64 + lane) * 8;
        bh[0][cf] = *(const f16x8*)(mh + off);
        bl[0][cf] = *(const f16x8*)(ml + off);
    }

    f32x4 acc[2][8];
    #pragma unroll
    for (int rf = 0; rf < 2; ++rf)
        #pragma unroll
        for (int cf = 0; cf < 8; ++cf)
            acc[rf][cf] = (f32x4){0.f, 0.f, 0.f, 0.f};

    // m97-proven drain: full waitcnt + block barrier.
    asm volatile("s_waitcnt vmcnt(0)" ::: "memory");
    __syncthreads();
    __builtin_amdgcn_sched_barrier(0);

    #pragma unroll
    for (int kk = 0; kk < 4; ++kk) {
        const int cur = kk & 1;
        if (kk < 3) {   // prefetch next kk's B (static indexing)
            const int nxt = cur ^ 1;
            #pragma unroll
            for (int cf = 0; cf < 8; ++cf) {
                const int off = (((kk + 1) * 8 + cf) * 64 + lane) * 8;
                bh[nxt][cf] = *(const f16x8*)(mh + off);
                bl[nxt][cf] = *(const f16x8*)(ml + off);
            }
        }

        // A fragments from swizzled LDS: row r, 16B slots t = q ^ (r&15).
        F16x8U a16[2];
        #pragma unroll
        for (int rf = 0; rf < 2; ++rf) {
            const int r  = w * 32 + rf * 16 + lrow;
            const int t0 = kk * 8 + lk * 2;
            F32x4U x, y;
            x.v = *(const f32x4*)&lds[(r * 32 + ((t0    ) ^ (r & 15))) * 4];
            y.v = *(const f32x4*)&lds[(r * 32 + ((t0 + 1) ^ (r & 15))) * 4];
            #pragma unroll
            for (int j = 0; j < 4; ++j) {
                a16[rf].h[j]     = (_Float16)x.f[j];
                a16[rf].h[j + 4] = (_Float16)y.f[j];
            }
        }

        #pragma unroll
        for (int rf = 0; rf < 2; ++rf)
            #pragma unroll
            for (int cf = 0; cf < 8; ++cf) {
                acc[rf][cf] = __builtin_amdgcn_mfma_f32_16x16x32_f16(
                    a16[rf].v, bh[cur][cf], acc[rf][cf], 0, 0, 0);
                acc[rf][cf] = __builtin_amdgcn_mfma_f32_16x16x32_f16(
                    a16[rf].v, bl[cur][cf], acc[rf][cf], 0, 0, 0);
            }
    }

    // Epilogue: C/D layout col=lane&15, row=(lane>>4)*4+i (m89-verified).
    // pi puts the 8 cf-values contiguous: Ep[row*128 + lrow*8 + cf].
    #pragma unroll
    for (int rf = 0; rf < 2; ++rf)
        #pragma unroll
        for (int i = 0; i < 4; ++i) {
            const int row = rb + w * 32 + rf * 16 + lk * 4 + i;
            if (row < NROWS) {
                F16x8U o;
                #pragma unroll
                for (int cf = 0; cf < 8; ++cf) o.h[cf] = (_Float16)acc[rf][cf][i];
                *(f16x8*)(Ep + (size_t)row * D + lrow * 8) = o.v;
            }
        }
}

// ---------------------------------------------------------------------------
// Kernel 3: out[b] = sigmoid(2 * dot(Ep[xs[b]], Np[ys[b]]) - 1).
// 16 lanes/output, 2 outputs per lane-group, fp32 accumulate.
// ---------------------------------------------------------------------------
__global__ __launch_bounds__(256) void gather_dot16(
    const int* __restrict__ xs, const int* __restrict__ ys,
    const _Float16* __restrict__ Ep, const _Float16* __restrict__ Np,
    float* __restrict__ out)
{
    const int tid = threadIdx.x;
    const int o0  = blockIdx.x * 32 + (tid >> 4) * 2;
    const int l   = tid & 15;

    const int x0 = xs[o0], x1 = xs[o0 + 1];
    const int y0 = ys[o0], y1 = ys[o0 + 1];

    const f16x8 a0 = *(const f16x8*)(Ep + (size_t)x0 * D + l * 8);
    const f16x8 b0 = *(const f16x8*)(Np + (size_t)y0 * D + l * 8);
    const f16x8 a1 = *(const f16x8*)(Ep + (size_t)x1 * D + l * 8);
    const f16x8 b1 = *(const f16x8*)(Np + (size_t)y1 * D + l * 8);

    float r0 = 0.f, r1 = 0.f;
    #pragma unroll
    for (int j = 0; j < 8; ++j) {
        r0 += (float)a0[j] * (float)b0[j];
        r1 += (float)a1[j] * (float)b1[j];
    }

    r0 += __shfl_xor(r0, 1); r1 += __shfl_xor(r1, 1);
    r0 += __shfl_xor(r0, 2); r1 += __shfl_xor(r1, 2);
    r0 += __shfl_xor(r0, 4); r1 += __shfl_xor(r1, 4);
    r0 += __shfl_xor(r0, 8); r1 += __shfl_xor(r1, 8);

    if (l == 0) {
        float2 v;
        v.x = 1.0f / (1.0f + __expf(1.0f - 2.0f * r0));
        v.y = 1.0f / (1.0f + __expf(1.0f - 2.0f * r1));
        *(float2*)(out + o0) = v;
    }
}

extern "C" void kernel_launch(void* const* d_in, const int* in_sizes, int n_in,
                              void* d_out, int out_size, void* d_ws, size_t ws_size,
                              hipStream_t stream) {
    const int*   xs     = (const int*)d_in[0];
    const int*   ys     = (const int*)d_in[1];
    const float* metric = (const float*)d_in[2];
    const float* EMBEDM = (const float*)d_in[3];
    const float* NEGEM  = (const float*)d_in[4];
    float*       out    = (float*)d_out;

    const int B = in_sizes[0];  // 262144

    // d_ws layout: Ep16 25.6MB @0, Np16 25.6MB @32MB, M-frag hi/lo @64MB.
    char* ws = (char*)d_ws;
    _Float16* Ep = (_Float16*)ws;
    _Float16* Np = (_Float16*)(ws + (32u << 20));
    _Float16* mh = (_Float16*)(ws + (64u << 20));
    _Float16* ml = (_Float16*)(ws + (64u << 20) + (64u << 10));

    convert_M16<<<8, 256, 0, stream>>>(metric, mh, ml);

    conv_N<<<NN, 256, 0, stream>>>(NEGEM, Np);

    gemm_E<<<NE, 256, 0, stream>>>(EMBEDM, mh, ml, Ep);

    gather_dot16<<<B / 32, 256, 0, stream>>>(xs, ys, Ep, Np, out);
}

// Round 7
// 55.385 us; speedup vs baseline: 1.2289x; 1.0909x over previous
//
#include <hip/hip_runtime.h>
#include <hip/hip_fp16.h>

#define D      128
#define NROWS  100000
#define RB     64                       // rows per E-block (32 KB LDS)
#define NE     ((NROWS + RB - 1) / RB)  // 1563
#define NN     (NROWS / 16)             // 6250
#define NPREP  (NE + NN)                // 7813; bid%5==0 -> E (exactly 1563)

typedef __attribute__((ext_vector_type(8))) _Float16 f16x8;
typedef __attribute__((ext_vector_type(2))) _Float16 f16x2;
typedef __attribute__((ext_vector_type(4))) float    f32x4;

union F16x8U { _Float16 h[8]; f16x8 v; };
union F32x4U { float f[4]; f32x4 v; };

typedef __attribute__((address_space(1))) const void gvoid;
typedef __attribute__((address_space(3))) void       lvoid;

// ---------------------------------------------------------------------------
// Kernel 0: metric -> fragment-ordered fp16 hi/lo B-fragments.
// Chunk q = (kk*8+cf)*64+lane holds B[k0+j][col], col=cf*16+(lane&15),
// k0=kk*32+(lane>>4)*8  == the 16x16x32 MFMA B-operand layout.
// fp16 two-term split: M = Mh + Ml, |residual| ~ 2^-22 |M|.
// ---------------------------------------------------------------------------
__global__ __launch_bounds__(256) void convert_M16(
    const float* __restrict__ M,
    _Float16* __restrict__ mh, _Float16* __restrict__ ml)
{
    const int q    = blockIdx.x * 256 + threadIdx.x;  // [0, 2048)
    const int kk   = q >> 9;
    const int cf   = (q >> 6) & 7;
    const int lane = q & 63;
    const int col  = cf * 16 + (lane & 15);
    const int k0   = kk * 32 + (lane >> 4) * 8;

    F16x8U h, l;
    #pragma unroll
    for (int j = 0; j < 8; ++j) {
        float f = M[(k0 + j) * D + col];
        _Float16 hh = (_Float16)f;
        h.h[j] = hh;
        l.h[j] = (_Float16)(f - (float)hh);
    }
    *(f16x8*)(mh + q * 8) = h.v;
    *(f16x8*)(ml + q * 8) = l.v;
}

// ---------------------------------------------------------------------------
// Kernel 1 (fused prep, interleaved grid):
//   bid % 5 == 0  -> E-GEMM block (64 rows x 128 cols), eid = bid/5
//   else          -> N-convert block (16 rows),        nid = bid - bid/5 - 1
// Interleaving co-schedules streaming N-waves with stalling E-waves on every
// CU so HBM stays saturated through the E drain phases.
//
// E path: stage 64x128 fp32 via global_load_lds (async), XOR-swizzled via
// pre-swizzled GLOBAL source (m173); proven drain = vmcnt(0)+__syncthreads.
// Wave w owns 32 COLS (cf = w*2+{0,1}) x all 64 rows: its 16 B-frags are
// loaded once into 64 VGPR (no double-buffer), acc[4][2]. Two-term fp16 MFMA.
// Output fp16 in pi order, pi(c) = (c&15)*8 + (c>>4).
//
// N path: row = nid*16 + (tid>>4); 8 dword loads at stride 64B (coalesced
// across 16 lanes) -> one pi-ordered 16B store.
// ---------------------------------------------------------------------------
__global__ __launch_bounds__(256, 3) void fused_prep4(
    const float* __restrict__ E, const float* __restrict__ N,
    const _Float16* __restrict__ mh, const _Float16* __restrict__ ml,
    _Float16* __restrict__ Ep, _Float16* __restrict__ Np)
{
    __shared__ float lds[RB * D];   // 32 KB

    const int tid = threadIdx.x;
    const int bid = (int)blockIdx.x;

    if (bid % 5 != 0) {
        // ---- N-convert ----
        const int nid = bid - bid / 5 - 1;              // 0..NN-1
        const int l16 = tid & 15;
        const int row = nid * 16 + (tid >> 4);          // exact: NN*16 = NROWS
        const float* src = N + (size_t)row * D + l16;
        F16x8U o;
        #pragma unroll
        for (int k = 0; k < 8; ++k) o.h[k] = (_Float16)src[16 * k];
        *(f16x8*)(Np + (size_t)row * D + l16 * 8) = o.v;
        return;
    }

    // ---- E-GEMM ----
    const int eid  = bid / 5;
    const int lane = tid & 63;
    const int w    = tid >> 6;
    const int rb   = eid * RB;
    const int lrow = lane & 15;
    const int lk   = lane >> 4;

    // Stage: 16B-slot S = w*512 + i*64 + lane; r = S>>5 (row), t = S&31;
    // global slot u = t ^ (r&15); LDS dest linear (wave-uniform base, HW adds
    // lane*16). Any wave may stage any rows (barrier below).
    #pragma unroll
    for (int i = 0; i < 8; ++i) {
        const int S  = w * 512 + i * 64 + lane;
        const int r  = S >> 5;
        const int u  = (S & 31) ^ (r & 15);
        const int gr = min(rb + r, NROWS - 1);          // tail clamp
        const float* src = E + (size_t)gr * D + u * 4;
        __builtin_amdgcn_global_load_lds(
            (gvoid*)src, (lvoid*)&lds[(w * 512 + i * 64) * 4], 16, 0, 0);
    }

    // Wave w's 16 B-fragments (cols w*32..+31), loaded ONCE (L2-hot).
    f16x8 bh[4][2], bl[4][2];
    #pragma unroll
    for (int kk = 0; kk < 4; ++kk)
        #pragma unroll
        for (int cfl = 0; cfl < 2; ++cfl) {
            const int off = ((kk * 8 + w * 2 + cfl) * 64 + lane) * 8;
            bh[kk][cfl] = *(const f16x8*)(mh + off);
            bl[kk][cfl] = *(const f16x8*)(ml + off);
        }

    f32x4 acc[4][2];
    #pragma unroll
    for (int rf = 0; rf < 4; ++rf)
        #pragma unroll
        for (int cfl = 0; cfl < 2; ++cfl)
            acc[rf][cfl] = (f32x4){0.f, 0.f, 0.f, 0.f};

    // Proven drain: full waitcnt + block barrier (R5's barrier-less variant raced).
    asm volatile("s_waitcnt vmcnt(0)" ::: "memory");
    __syncthreads();
    __builtin_amdgcn_sched_barrier(0);

    #pragma unroll
    for (int kk = 0; kk < 4; ++kk) {
        // A fragments: row r = rf*16 + lrow, 16B slot t = (kk*8+lk*2) ^ (r&15).
        F16x8U a16[4];
        #pragma unroll
        for (int rf = 0; rf < 4; ++rf) {
            const int r  = rf * 16 + lrow;
            const int t0 = kk * 8 + lk * 2;
            F32x4U x, y;
            x.v = *(const f32x4*)&lds[(r * 32 + ((t0    ) ^ (r & 15))) * 4];
            y.v = *(const f32x4*)&lds[(r * 32 + ((t0 + 1) ^ (r & 15))) * 4];
            #pragma unroll
            for (int j = 0; j < 4; ++j) {
                a16[rf].h[j]     = (_Float16)x.f[j];
                a16[rf].h[j + 4] = (_Float16)y.f[j];
            }
        }

        #pragma unroll
        for (int rf = 0; rf < 4; ++rf)
            #pragma unroll
            for (int cfl = 0; cfl < 2; ++cfl) {
                acc[rf][cfl] = __builtin_amdgcn_mfma_f32_16x16x32_f16(
                    a16[rf].v, bh[kk][cfl], acc[rf][cfl], 0, 0, 0);
                acc[rf][cfl] = __builtin_amdgcn_mfma_f32_16x16x32_f16(
                    a16[rf].v, bl[kk][cfl], acc[rf][cfl], 0, 0, 0);
            }
    }

    // Epilogue: C/D layout col=lane&15, row=(lane>>4)*4+i (m89-verified).
    // Global col c = w*32 + cfl*16 + lrow; pi(c) = lrow*8 + w*2 + cfl ->
    // per-(rf,i) the 2 cfl values are adjacent: one f16x2 (4B) store.
    #pragma unroll
    for (int rf = 0; rf < 4; ++rf)
        #pragma unroll
        for (int i = 0; i < 4; ++i) {
            const int row = rb + rf * 16 + lk * 4 + i;
            if (row < NROWS) {
                f16x2 o;
                o[0] = (_Float16)acc[rf][0][i];
                o[1] = (_Float16)acc[rf][1][i];
                *(f16x2*)(Ep + (size_t)row * D + lrow * 8 + w * 2) = o;
            }
        }
}

// ---------------------------------------------------------------------------
// Kernel 2: out[b] = sigmoid(2 * dot(Ep[xs[b]], Np[ys[b]]) - 1).
// 16 lanes/output, 2 outputs per lane-group, fp32 accumulate.
// ---------------------------------------------------------------------------
__global__ __launch_bounds__(256) void gather_dot16(
    const int* __restrict__ xs, const int* __restrict__ ys,
    const _Float16* __restrict__ Ep, const _Float16* __restrict__ Np,
    float* __restrict__ out)
{
    const int tid = threadIdx.x;
    const int o0  = blockIdx.x * 32 + (tid >> 4) * 2;
    const int l   = tid & 15;

    const int x0 = xs[o0], x1 = xs[o0 + 1];
    const int y0 = ys[o0], y1 = ys[o0 + 1];

    const f16x8 a0 = *(const f16x8*)(Ep + (size_t)x0 * D + l * 8);
    const f16x8 b0 = *(const f16x8*)(Np + (size_t)y0 * D + l * 8);
    const f16x8 a1 = *(const f16x8*)(Ep + (size_t)x1 * D + l * 8);
    const f16x8 b1 = *(const f16x8*)(Np + (size_t)y1 * D + l * 8);

    float r0 = 0.f, r1 = 0.f;
    #pragma unroll
    for (int j = 0; j < 8; ++j) {
        r0 += (float)a0[j] * (float)b0[j];
        r1 += (float)a1[j] * (float)b1[j];
    }

    r0 += __shfl_xor(r0, 1); r1 += __shfl_xor(r1, 1);
    r0 += __shfl_xor(r0, 2); r1 += __shfl_xor(r1, 2);
    r0 += __shfl_xor(r0, 4); r1 += __shfl_xor(r1, 4);
    r0 += __shfl_xor(r0, 8); r1 += __shfl_xor(r1, 8);

    if (l == 0) {
        float2 v;
        v.x = 1.0f / (1.0f + __expf(1.0f - 2.0f * r0));
        v.y = 1.0f / (1.0f + __expf(1.0f - 2.0f * r1));
        *(float2*)(out + o0) = v;
    }
}

extern "C" void kernel_launch(void* const* d_in, const int* in_sizes, int n_in,
                              void* d_out, int out_size, void* d_ws, size_t ws_size,
                              hipStream_t stream) {
    const int*   xs     = (const int*)d_in[0];
    const int*   ys     = (const int*)d_in[1];
    const float* metric = (const float*)d_in[2];
    const float* EMBEDM = (const float*)d_in[3];
    const float* NEGEM  = (const float*)d_in[4];
    float*       out    = (float*)d_out;

    const int B = in_sizes[0];  // 262144

    // d_ws layout: Ep16 25.6MB @0, Np16 25.6MB @32MB, M-frag hi/lo @64MB.
    char* ws = (char*)d_ws;
    _Float16* Ep = (_Float16*)ws;
    _Float16* Np = (_Float16*)(ws + (32u << 20));
    _Float16* mh = (_Float16*)(ws + (64u << 20));
    _Float16* ml = (_Float16*)(ws + (64u << 20) + (64u << 10));

    convert_M16<<<8, 256, 0, stream>>>(metric, mh, ml);

    fused_prep4<<<NPREP, 256, 0, stream>>>(EMBEDM, NEGEM, mh, ml, Ep, Np);

    gather_dot16<<<B / 32, 256, 0, stream>>>(xs, ys, Ep, Np, out);
}